// Round 10
// baseline (321.876 us; speedup 1.0000x reference)
//
#include <hip/hip_runtime.h>
#include <hip/hip_bf16.h>

#define N_NODES 50000
#define N_EDGES 819200
#define NUM_RELS 8
#define EPR (N_EDGES / NUM_RELS) /* 102400 */
#define N_HEADS 4
#define IN_FEAT 256
#define OUT_FEAT 128
#define HEAD_DIM 32
#define NB_SCAN ((N_NODES + 255) / 256) /* 196 */

typedef __attribute__((ext_vector_type(8))) __bf16 bf16x8;
typedef __attribute__((ext_vector_type(4))) __bf16 bf16x4;
typedef __attribute__((ext_vector_type(4))) float f32x4;

// ---- workspace layout (float units) ----
#define SZ_FEAT ((size_t)NUM_RELS * N_NODES * OUT_FEAT)
#define SZ_EL ((size_t)NUM_RELS * N_NODES * N_HEADS)
#define SZ_WB ((size_t)IN_FEAT * 64) /* wbt (8192 floats) + wbg (8192 floats) */
#define SZ_WT ((size_t)NUM_RELS * OUT_FEAT * IN_FEAT / 2)
#define OFF_FEAT ((size_t)0)
#define OFF_EL (OFF_FEAT + SZ_FEAT)
#define OFF_ER (OFF_EL + SZ_EL)
#define OFF_WB (OFF_ER + SZ_EL)
#define OFF_WT (OFF_WB + SZ_WB)
#define OFF_INT (OFF_WT + SZ_WT)
#define IOFF_CNT ((size_t)0)
#define IOFF_PTR ((size_t)N_NODES)
#define IOFF_CUR ((size_t)2 * N_NODES)
#define IOFF_BSUM ((size_t)3 * N_NODES)
#define IOFF_SPAY ((size_t)3 * N_NODES + 256)

// weights -> fragment-ordered image: frag idx = (((r*4+kc)*2+ks)*128 + brow)*4 + oct
// frag holds bf16 k-octet: k = kc*64+ks*32+oct*8, output brow = h*32+d
__global__ void k_cvtw(const float* __restrict__ cw, __bf16* __restrict__ wtg) {
    int tid = blockIdx.x * blockDim.x + threadIdx.x;
    if (tid >= 32768) return;
    int oct = tid & 3, brow = (tid >> 2) & 127, ks = (tid >> 9) & 1, kc = (tid >> 10) & 3, r = tid >> 12;
    int k0 = kc * 64 + ks * 32 + oct * 8;
    int h = brow >> 5, d = brow & 31;
    const float* src = cw + ((size_t)(r * N_HEADS + h) * IN_FEAT + k0) * HEAD_DIM + d;
    bf16x8 v;
#pragma unroll
    for (int j = 0; j < 8; ++j) v[j] = (__bf16)src[j * HEAD_DIM];
    *(bf16x8*)(wtg + (size_t)tid * 8) = v;
}

// folded attention vectors, transposed bf16: wbt[col][k], col = side*32+r*4+h
__global__ void k_wboth(const float* __restrict__ cw, const float* __restrict__ al,
                        const float* __restrict__ ar, __bf16* __restrict__ wbt) {
    int tid = blockIdx.x * blockDim.x + threadIdx.x;
    if (tid >= IN_FEAT * 64) return;
    int col = tid >> 8, i = tid & 255;
    int side = col >> 5, r = (col >> 2) & 7, h = col & 3;
    const float* av = (side ? ar : al) + (size_t)(r * N_HEADS + h) * HEAD_DIM;
    const float* cwp = cw + ((size_t)(r * N_HEADS + h) * IN_FEAT + i) * HEAD_DIM;
    float s = 0.f;
#pragma unroll
    for (int d = 0; d < HEAD_DIM; ++d) s += cwp[d] * av[d];
    wbt[(size_t)col * IN_FEAT + i] = (__bf16)s;
}

// wbt -> fragment image: idx = ((kc*2+ks)*64 + brow)*4 + oct
__global__ void k_wbg(const __bf16* __restrict__ wbt, __bf16* __restrict__ wbg) {
    int tid = blockIdx.x * blockDim.x + threadIdx.x;
    if (tid >= 2048) return;
    int oct = tid & 3, brow = (tid >> 2) & 63, ks = (tid >> 8) & 1, kc = tid >> 9;
    int k0 = kc * 64 + ks * 32 + oct * 8;
    bf16x8 v = *(const bf16x8*)(wbt + (size_t)brow * IN_FEAT + k0);
    *(bf16x8*)(wbg + (size_t)tid * 8) = v;
}

// per-wave B frags (16 cols): brow = wc*16 + (lane&15), oct = lane>>4
__device__ __forceinline__ void loadB(bf16x8 (&dst)[2], const __bf16* __restrict__ wtg,
                                      int r, int kc, int wc, int lane) {
#pragma unroll
    for (int ks = 0; ks < 2; ++ks)
        dst[ks] = *(const bf16x8*)(wtg +
            ((size_t)((((r * 4 + kc) * 2 + ks) * 128) + wc * 16 + (lane & 15)) * 4 + (lane >> 4)) * 8);
}

__device__ __forceinline__ void loadB2(bf16x8 (&dst)[2], const __bf16* __restrict__ wbg,
                                       int wc, int kc, int lane) {
#pragma unroll
    for (int ks = 0; ks < 2; ++ks)
        dst[ks] = *(const bf16x8*)(wbg +
            ((size_t)(((kc * 2 + ks) * 64) + wc * 16 + (lane & 15)) * 4 + (lane >> 4)) * 8);
}

// one kc step: 8 ds_read (4 rb x 2 ks) + 8 MFMA into acc[4]
__device__ __forceinline__ void compK(f32x4 (&acc)[4], const unsigned char* sA,
                                      const bf16x8 (&bg)[2], int kc, int wr, int lane) {
#pragma unroll
    for (int ks = 0; ks < 2; ++ks) {
        bf16x8 af[4];
#pragma unroll
        for (int rb = 0; rb < 4; ++rb) {
            int rowa = wr * 64 + rb * 16 + (lane & 15);
            int slot = kc * 8 + ((ks * 4 + (lane >> 4)) ^ (rowa & 7));
            af[rb] = *(const bf16x8*)(sA + rowa * 512 + slot * 16);
        }
#pragma unroll
        for (int rb = 0; rb < 4; ++rb)
            acc[rb] = __builtin_amdgcn_mfma_f32_16x16x32_bf16(af[rb], bg[ks], acc[rb], 0, 0, 0);
    }
}

// Fused transform: A in LDS (staged once, ONE barrier), B streamed global->VGPR,
// no main-loop barriers. 128-node tile, 16 waves (2 wave-rows x 8 wave-cols).
__global__ __launch_bounds__(1024, 4) void k_fused(const float* __restrict__ x,
                                                   const __bf16* __restrict__ wtg,
                                                   const __bf16* __restrict__ wbg,
                                                   __bf16* __restrict__ featb,
                                                   float* __restrict__ el,
                                                   float* __restrict__ er) {
    __shared__ __align__(16) unsigned char sA[65536]; // [128 rows][512B] swizzled
    const int t = threadIdx.x, lane = t & 63, w = t >> 6;
    const int wr = w >> 3, wc = w & 7;
    const int n0 = blockIdx.x * 128;

    // ---- stage A once: 128 rows x 256 k, fp32 -> bf16, swizzled ds_write ----
#pragma unroll
    for (int i = 0; i < 8; ++i) {
        int flat = i * 1024 + t;  // 0..8191 float4 units
        int row = flat >> 6;      // 0..127
        int kq = flat & 63;       // k = kq*4
        int n = n0 + row;
        if (n >= N_NODES) n = N_NODES - 1;
        float4 v = *(const float4*)(x + (size_t)n * IN_FEAT + kq * 4);
        bf16x4 hv;
        hv[0] = (__bf16)v.x; hv[1] = (__bf16)v.y; hv[2] = (__bf16)v.z; hv[3] = (__bf16)v.w;
        int sg = kq >> 1;
        int slot = (sg & ~7) | ((sg & 7) ^ (row & 7));
        *(bf16x4*)(sA + row * 512 + slot * 16 + (kq & 1) * 8) = hv;
    }
    __syncthreads();

    // ---- 8 relation passes, B double-buffered in registers ----
    bf16x8 bgA[2], bgB[2];
    for (int r = 0; r < NUM_RELS; ++r) {
        f32x4 acc[4];
#pragma unroll
        for (int i = 0; i < 4; ++i) acc[i] = (f32x4){0.f, 0.f, 0.f, 0.f};

        loadB(bgA, wtg, r, 0, wc, lane);
        loadB(bgB, wtg, r, 1, wc, lane);
        compK(acc, sA, bgA, 0, wr, lane);
        loadB(bgA, wtg, r, 2, wc, lane);
        compK(acc, sA, bgB, 1, wr, lane);
        loadB(bgB, wtg, r, 3, wc, lane);
        compK(acc, sA, bgA, 2, wr, lane);
        compK(acc, sA, bgB, 3, wr, lane);

        // epilogue rel r (C map: col=lane&15, row=(lane>>4)*4+q)
#pragma unroll
        for (int rb = 0; rb < 4; ++rb)
#pragma unroll
            for (int q = 0; q < 4; ++q) {
                int rowi = wr * 64 + rb * 16 + (lane >> 4) * 4 + q;
                int n = n0 + rowi;
                if (n < N_NODES)
                    featb[((size_t)r * N_NODES + n) * OUT_FEAT + wc * 16 + (lane & 15)] =
                        (__bf16)acc[rb][q];
            }
    }

    // ---- el/er pass: 64 cols -> wave-cols 0..3 only ----
    if (wc < 4) {
        f32x4 acc2[4];
#pragma unroll
        for (int i = 0; i < 4; ++i) acc2[i] = (f32x4){0.f, 0.f, 0.f, 0.f};
        bf16x8 cgA[2], cgB[2];
        loadB2(cgA, wbg, wc, 0, lane);
        loadB2(cgB, wbg, wc, 1, lane);
        compK(acc2, sA, cgA, 0, wr, lane);
        loadB2(cgA, wbg, wc, 2, lane);
        compK(acc2, sA, cgB, 1, wr, lane);
        loadB2(cgB, wbg, wc, 3, lane);
        compK(acc2, sA, cgA, 2, wr, lane);
        compK(acc2, sA, cgB, 3, wr, lane);

#pragma unroll
        for (int rb = 0; rb < 4; ++rb)
#pragma unroll
            for (int q = 0; q < 4; ++q) {
                int n = n0 + wr * 64 + rb * 16 + (lane >> 4) * 4 + q;
                if (n < N_NODES) {
                    int c = wc * 16 + (lane & 15);
                    int side = c >> 5, rr = (c >> 2) & 7, h = c & 3;
                    float* dst = side ? er : el;
                    dst[((size_t)rr * N_NODES + n) * N_HEADS + h] = acc2[rb][q];
                }
            }
    }
}

// ---- CSR build ----
__global__ void k_hist(const int* __restrict__ col, int* __restrict__ cnt) {
    int e = blockIdx.x * blockDim.x + threadIdx.x;
    if (e < N_EDGES) atomicAdd(cnt + col[e], 1);
}

__global__ __launch_bounds__(256) void k_scanA(const int* __restrict__ cnt,
                                               int* __restrict__ excl,
                                               int* __restrict__ bsum) {
    __shared__ int s[256];
    int i = blockIdx.x * 256 + threadIdx.x;
    int v = (i < N_NODES) ? cnt[i] : 0;
    s[threadIdx.x] = v;
    __syncthreads();
#pragma unroll
    for (int off = 1; off < 256; off <<= 1) {
        int t = (threadIdx.x >= off) ? s[threadIdx.x - off] : 0;
        __syncthreads();
        s[threadIdx.x] += t;
        __syncthreads();
    }
    if (i < N_NODES) excl[i] = s[threadIdx.x] - v;
    if (threadIdx.x == 255) bsum[blockIdx.x] = s[255];
}

__global__ __launch_bounds__(256) void k_scanB(int* __restrict__ bsum) {
    __shared__ int s[256];
    int v = (threadIdx.x < NB_SCAN) ? bsum[threadIdx.x] : 0;
    s[threadIdx.x] = v;
    __syncthreads();
#pragma unroll
    for (int off = 1; off < 256; off <<= 1) {
        int t = (threadIdx.x >= off) ? s[threadIdx.x - off] : 0;
        __syncthreads();
        s[threadIdx.x] += t;
        __syncthreads();
    }
    bsum[threadIdx.x] = s[threadIdx.x] - v;
}

__global__ __launch_bounds__(256) void k_scanC(int* __restrict__ ptr,
                                               int* __restrict__ cursor,
                                               const int* __restrict__ bsum) {
    int i = blockIdx.x * 256 + threadIdx.x;
    if (i >= N_NODES) return;
    int p = ptr[i] + bsum[blockIdx.x];
    ptr[i] = p;
    cursor[i] = p;
}

__global__ void k_scatter(const int* __restrict__ row, const int* __restrict__ col,
                          int* __restrict__ cursor, int* __restrict__ spay) {
    int e = blockIdx.x * blockDim.x + threadIdx.x;
    if (e >= N_EDGES) return;
    int c = col[e];
    int pos = atomicAdd(cursor + c, 1);
    spay[pos] = row[e] | ((e / EPR) << 20);
}

// pull-aggregation, bf16 feat gather, 4-deep explicit pipeline
__global__ __launch_bounds__(256) void k_agg(const int* __restrict__ ptr,
                                             const int* __restrict__ cnt,
                                             const int* __restrict__ spay,
                                             const float* __restrict__ el,
                                             const float* __restrict__ er,
                                             const __bf16* __restrict__ featb,
                                             const float* __restrict__ bias,
                                             float* __restrict__ out) {
    const int wv = threadIdx.x >> 6, lane = threadIdx.x & 63;
    const int n = blockIdx.x * 4 + wv;
    if (n >= N_NODES) return;
    const int start = ptr[n], len = cnt[n];
    const int h = lane >> 4;
    float accx = 0.f, accy = 0.f, den = 0.f;
    int j = 0;
    for (; j + 4 <= len; j += 4) {
        int p[4];
#pragma unroll
        for (int u = 0; u < 4; ++u) p[u] = spay[start + j + u];
        float w[4], vx[4], vy[4];
#pragma unroll
        for (int u = 0; u < 4; ++u) {
            int rw = p[u] & 0xFFFFF, r = p[u] >> 20;
            size_t rb = (size_t)r * N_NODES;
            float s = el[(rb + rw) * N_HEADS + h] + er[(rb + n) * N_HEADS + h];
            s = s > 0.f ? s : 0.2f * s;
            w[u] = __expf(s);
            ushort2 raw = *(const ushort2*)(featb + (rb + rw) * OUT_FEAT + lane * 2);
            vx[u] = __uint_as_float((unsigned)raw.x << 16);
            vy[u] = __uint_as_float((unsigned)raw.y << 16);
        }
#pragma unroll
        for (int u = 0; u < 4; ++u) {
            accx += w[u] * vx[u];
            accy += w[u] * vy[u];
            den += w[u];
        }
    }
    for (; j < len; ++j) {
        int p = spay[start + j];
        int rw = p & 0xFFFFF, r = p >> 20;
        size_t rb = (size_t)r * N_NODES;
        float s = el[(rb + rw) * N_HEADS + h] + er[(rb + n) * N_HEADS + h];
        s = s > 0.f ? s : 0.2f * s;
        float w = __expf(s);
        ushort2 raw = *(const ushort2*)(featb + (rb + rw) * OUT_FEAT + lane * 2);
        accx += w * __uint_as_float((unsigned)raw.x << 16);
        accy += w * __uint_as_float((unsigned)raw.y << 16);
        den += w;
    }
    float inv = (len > 0) ? 1.f / den : 0.f;
    int o = lane * 2;
    float2 res;
    res.x = accx * inv + bias[o];
    res.y = accy * inv + bias[o + 1];
    *(float2*)(out + (size_t)n * OUT_FEAT + o) = res;
}

extern "C" void kernel_launch(void* const* d_in, const int* in_sizes, int n_in,
                              void* d_out, int out_size, void* d_ws, size_t ws_size,
                              hipStream_t stream) {
    const float* x = (const float*)d_in[0];
    const float* cw = (const float*)d_in[1];
    const float* al = (const float*)d_in[2];
    const float* ar = (const float*)d_in[3];
    const float* bias = (const float*)d_in[4];
    const int* row = (const int*)d_in[5];
    const int* col = (const int*)d_in[6];
    float* out = (float*)d_out;
    float* ws = (float*)d_ws;

    __bf16* featb = (__bf16*)(ws + OFF_FEAT);
    float* el = ws + OFF_EL;
    float* er = ws + OFF_ER;
    __bf16* wbt = (__bf16*)(ws + OFF_WB);
    __bf16* wbg = (__bf16*)(ws + OFF_WB + 8192);
    __bf16* wtg = (__bf16*)(ws + OFF_WT);
    int* iw = (int*)(ws + OFF_INT);
    int* cnt = iw + IOFF_CNT;
    int* ptr = iw + IOFF_PTR;
    int* cur = iw + IOFF_CUR;
    int* bsum = iw + IOFF_BSUM;
    int* spay = iw + IOFF_SPAY;

    hipMemsetAsync(cnt, 0, N_NODES * sizeof(int), stream);

    k_cvtw<<<128, 256, 0, stream>>>(cw, wtg);
    k_wboth<<<(IN_FEAT * 64 + 255) / 256, 256, 0, stream>>>(cw, al, ar, wbt);
    k_wbg<<<8, 256, 0, stream>>>(wbt, wbg);
    k_fused<<<(N_NODES + 127) / 128, 1024, 0, stream>>>(x, wtg, wbg, featb, el, er);

    k_hist<<<(N_EDGES + 255) / 256, 256, 0, stream>>>(col, cnt);
    k_scanA<<<NB_SCAN, 256, 0, stream>>>(cnt, ptr, bsum);
    k_scanB<<<1, 256, 0, stream>>>(bsum);
    k_scanC<<<NB_SCAN, 256, 0, stream>>>(ptr, cur, bsum);
    k_scatter<<<(N_EDGES + 255) / 256, 256, 0, stream>>>(row, col, cur, spay);

    k_agg<<<(N_NODES + 3) / 4, 256, 0, stream>>>(ptr, cnt, spay, el, er, featb, bias, out);
}

// Round 11
// 259.875 us; speedup vs baseline: 1.2386x; 1.2386x over previous
//
#include <hip/hip_runtime.h>
#include <hip/hip_bf16.h>

#define N_NODES 50000
#define N_EDGES 819200
#define NUM_RELS 8
#define EPR (N_EDGES / NUM_RELS) /* 102400 */
#define N_HEADS 4
#define IN_FEAT 256
#define OUT_FEAT 128
#define HEAD_DIM 32
#define NB_SCAN ((N_NODES + 255) / 256) /* 196 */

typedef __attribute__((ext_vector_type(8))) __bf16 bf16x8;
typedef __attribute__((ext_vector_type(4))) __bf16 bf16x4;
typedef __attribute__((ext_vector_type(4))) float f32x4;

// ---- workspace layout (float units) ----
#define SZ_FEAT ((size_t)NUM_RELS * N_NODES * OUT_FEAT)
#define SZ_EL ((size_t)NUM_RELS * N_NODES * N_HEADS)
#define SZ_WB ((size_t)IN_FEAT * 64) /* wbt (8192 floats) + wbg (8192 floats) */
#define SZ_WT ((size_t)NUM_RELS * OUT_FEAT * IN_FEAT / 2)
#define OFF_FEAT ((size_t)0)
#define OFF_EL (OFF_FEAT + SZ_FEAT)
#define OFF_ER (OFF_EL + SZ_EL)
#define OFF_WB (OFF_ER + SZ_EL)
#define OFF_WT (OFF_WB + SZ_WB)
#define OFF_INT (OFF_WT + SZ_WT)
#define IOFF_CNT ((size_t)0)
#define IOFF_PTR ((size_t)N_NODES)
#define IOFF_CUR ((size_t)2 * N_NODES)
#define IOFF_BSUM ((size_t)3 * N_NODES)
#define IOFF_SPAY ((size_t)3 * N_NODES + 256)

// weights -> fragment-ordered image: frag idx = (((r*4+kc)*2+ks)*128 + brow)*4 + oct
// frag holds bf16 k-octet: k = kc*64+ks*32+oct*8, output brow = h*32+d
__global__ void k_cvtw(const float* __restrict__ cw, __bf16* __restrict__ wtg) {
    int tid = blockIdx.x * blockDim.x + threadIdx.x;
    if (tid >= 32768) return;
    int oct = tid & 3, brow = (tid >> 2) & 127, ks = (tid >> 9) & 1, kc = (tid >> 10) & 3, r = tid >> 12;
    int k0 = kc * 64 + ks * 32 + oct * 8;
    int h = brow >> 5, d = brow & 31;
    const float* src = cw + ((size_t)(r * N_HEADS + h) * IN_FEAT + k0) * HEAD_DIM + d;
    bf16x8 v;
#pragma unroll
    for (int j = 0; j < 8; ++j) v[j] = (__bf16)src[j * HEAD_DIM];
    *(bf16x8*)(wtg + (size_t)tid * 8) = v;
}

// folded attention vectors, transposed bf16: wbt[col][k], col = side*32+r*4+h
__global__ void k_wboth(const float* __restrict__ cw, const float* __restrict__ al,
                        const float* __restrict__ ar, __bf16* __restrict__ wbt) {
    int tid = blockIdx.x * blockDim.x + threadIdx.x;
    if (tid >= IN_FEAT * 64) return;
    int col = tid >> 8, i = tid & 255;
    int side = col >> 5, r = (col >> 2) & 7, h = col & 3;
    const float* av = (side ? ar : al) + (size_t)(r * N_HEADS + h) * HEAD_DIM;
    const float* cwp = cw + ((size_t)(r * N_HEADS + h) * IN_FEAT + i) * HEAD_DIM;
    float s = 0.f;
#pragma unroll
    for (int d = 0; d < HEAD_DIM; ++d) s += cwp[d] * av[d];
    wbt[(size_t)col * IN_FEAT + i] = (__bf16)s;
}

// wbt -> fragment image: idx = ((kc*2+ks)*64 + brow)*4 + oct
__global__ void k_wbg(const __bf16* __restrict__ wbt, __bf16* __restrict__ wbg) {
    int tid = blockIdx.x * blockDim.x + threadIdx.x;
    if (tid >= 2048) return;
    int oct = tid & 3, brow = (tid >> 2) & 63, ks = (tid >> 8) & 1, kc = tid >> 9;
    int k0 = kc * 64 + ks * 32 + oct * 8;
    bf16x8 v = *(const bf16x8*)(wbt + (size_t)brow * IN_FEAT + k0);
    *(bf16x8*)(wbg + (size_t)tid * 8) = v;
}

// per-wave B frags (64 cols): brow = wc*64 + cb*16 + (lane&15), oct = lane>>4
__device__ __forceinline__ void loadB(bf16x8 (&dst)[8], const __bf16* __restrict__ wtg,
                                      int r, int kc, int wc, int lane) {
#pragma unroll
    for (int ks = 0; ks < 2; ++ks)
#pragma unroll
        for (int cb = 0; cb < 4; ++cb)
            dst[ks * 4 + cb] = *(const bf16x8*)(wtg +
                ((size_t)((((r * 4 + kc) * 2 + ks) * 128) + wc * 64 + cb * 16 + (lane & 15)) * 4 + (lane >> 4)) * 8);
}

__device__ __forceinline__ void loadB2(bf16x8 (&dst)[4], const __bf16* __restrict__ wbg,
                                       int kc, int wc, int lane) {
#pragma unroll
    for (int ks = 0; ks < 2; ++ks)
#pragma unroll
        for (int cb = 0; cb < 2; ++cb)
            dst[ks * 2 + cb] = *(const bf16x8*)(wbg +
                ((size_t)(((kc * 2 + ks) * 64) + wc * 32 + cb * 16 + (lane & 15)) * 4 + (lane >> 4)) * 8);
}

// one kc step: 4 ds_read (2 rb x 2 ks) + 16 MFMA into acc[2][4]
__device__ __forceinline__ void compK(f32x4 (&acc)[2][4], const unsigned char* sA,
                                      const bf16x8 (&bg)[8], int kc, int wr, int lane) {
#pragma unroll
    for (int ks = 0; ks < 2; ++ks) {
        bf16x8 af[2];
#pragma unroll
        for (int rb = 0; rb < 2; ++rb) {
            int rowa = wr * 32 + rb * 16 + (lane & 15);
            int slot = kc * 8 + ((ks * 4 + (lane >> 4)) ^ (rowa & 7));
            af[rb] = *(const bf16x8*)(sA + rowa * 512 + slot * 16);
        }
#pragma unroll
        for (int rb = 0; rb < 2; ++rb)
#pragma unroll
            for (int cb = 0; cb < 4; ++cb)
                acc[rb][cb] = __builtin_amdgcn_mfma_f32_16x16x32_bf16(af[rb], bg[ks * 4 + cb], acc[rb][cb], 0, 0, 0);
    }
}

__device__ __forceinline__ void compK2(f32x4 (&acc2)[2][2], const unsigned char* sA,
                                       const bf16x8 (&bg)[4], int kc, int wr, int lane) {
#pragma unroll
    for (int ks = 0; ks < 2; ++ks) {
        bf16x8 af[2];
#pragma unroll
        for (int rb = 0; rb < 2; ++rb) {
            int rowa = wr * 32 + rb * 16 + (lane & 15);
            int slot = kc * 8 + ((ks * 4 + (lane >> 4)) ^ (rowa & 7));
            af[rb] = *(const bf16x8*)(sA + rowa * 512 + slot * 16);
        }
#pragma unroll
        for (int rb = 0; rb < 2; ++rb)
#pragma unroll
            for (int cb = 0; cb < 2; ++cb)
                acc2[rb][cb] = __builtin_amdgcn_mfma_f32_16x16x32_bf16(af[rb], bg[ks * 2 + cb], acc2[rb][cb], 0, 0, 0);
    }
}

// Fused transform: A in LDS (staged once, ONE barrier), B streamed global->VGPR,
// no main-loop barriers. 64-node tile (782 blocks ~ 3/CU), 4 waves 2x2.
__global__ __launch_bounds__(256, 3) void k_fused(const float* __restrict__ x,
                                                  const __bf16* __restrict__ wtg,
                                                  const __bf16* __restrict__ wbg,
                                                  __bf16* __restrict__ featb,
                                                  float* __restrict__ el,
                                                  float* __restrict__ er) {
    __shared__ __align__(16) unsigned char sA[32768]; // [64 rows][512B] swizzled
    const int t = threadIdx.x, lane = t & 63, w = t >> 6;
    const int wr = w >> 1, wc = w & 1;
    const int n0 = blockIdx.x * 64;

    // ---- stage A once: 64 rows x 256 k, fp32 -> bf16, swizzled ds_write ----
#pragma unroll
    for (int i = 0; i < 16; ++i) {
        int flat = i * 256 + t;   // 0..4095 float4 units
        int row = flat >> 6;      // 0..63
        int kq = flat & 63;       // k = kq*4
        int n = n0 + row;
        if (n >= N_NODES) n = N_NODES - 1;
        float4 v = *(const float4*)(x + (size_t)n * IN_FEAT + kq * 4);
        bf16x4 hv;
        hv[0] = (__bf16)v.x; hv[1] = (__bf16)v.y; hv[2] = (__bf16)v.z; hv[3] = (__bf16)v.w;
        int sg = kq >> 1;
        int slot = (sg & ~7) | ((sg & 7) ^ (row & 7));
        *(bf16x4*)(sA + row * 512 + slot * 16 + (kq & 1) * 8) = hv;
    }
    __syncthreads();

    // ---- 8 relation passes, B double-buffered in registers ----
    bf16x8 bgA[8], bgB[8];
    for (int r = 0; r < NUM_RELS; ++r) {
        f32x4 acc[2][4];
#pragma unroll
        for (int i = 0; i < 2; ++i)
#pragma unroll
            for (int j = 0; j < 4; ++j) acc[i][j] = (f32x4){0.f, 0.f, 0.f, 0.f};

        loadB(bgA, wtg, r, 0, wc, lane);
        loadB(bgB, wtg, r, 1, wc, lane);
        compK(acc, sA, bgA, 0, wr, lane);
        loadB(bgA, wtg, r, 2, wc, lane);
        compK(acc, sA, bgB, 1, wr, lane);
        loadB(bgB, wtg, r, 3, wc, lane);
        compK(acc, sA, bgA, 2, wr, lane);
        compK(acc, sA, bgB, 3, wr, lane);

        // epilogue rel r (C map: col=lane&15, row=(lane>>4)*4+q); 4 adjacent cb
        // segments per row-set -> write-combines to full lines (R9-clean pattern)
#pragma unroll
        for (int rb = 0; rb < 2; ++rb)
#pragma unroll
            for (int q = 0; q < 4; ++q) {
                int rowi = wr * 32 + rb * 16 + (lane >> 4) * 4 + q;
                int n = n0 + rowi;
                if (n < N_NODES) {
                    __bf16* fp = featb + ((size_t)r * N_NODES + n) * OUT_FEAT + wc * 64 + (lane & 15);
#pragma unroll
                    for (int cb = 0; cb < 4; ++cb) fp[cb * 16] = (__bf16)acc[rb][cb][q];
                }
            }
    }

    // ---- el/er pass ----
    f32x4 acc2[2][2];
#pragma unroll
    for (int i = 0; i < 2; ++i)
#pragma unroll
        for (int j = 0; j < 2; ++j) acc2[i][j] = (f32x4){0.f, 0.f, 0.f, 0.f};

    bf16x8 cgA[4], cgB[4];
    loadB2(cgA, wbg, 0, wc, lane);
    loadB2(cgB, wbg, 1, wc, lane);
    compK2(acc2, sA, cgA, 0, wr, lane);
    loadB2(cgA, wbg, 2, wc, lane);
    compK2(acc2, sA, cgB, 1, wr, lane);
    loadB2(cgB, wbg, 3, wc, lane);
    compK2(acc2, sA, cgA, 2, wr, lane);
    compK2(acc2, sA, cgB, 3, wr, lane);

#pragma unroll
    for (int rb = 0; rb < 2; ++rb)
#pragma unroll
        for (int q = 0; q < 4; ++q) {
            int n = n0 + wr * 32 + rb * 16 + (lane >> 4) * 4 + q;
            if (n < N_NODES) {
#pragma unroll
                for (int cb = 0; cb < 2; ++cb) {
                    int c = wc * 32 + cb * 16 + (lane & 15);
                    int side = c >> 5, rr = (c >> 2) & 7, h = c & 3;
                    float* dst = side ? er : el;
                    dst[((size_t)rr * N_NODES + n) * N_HEADS + h] = acc2[rb][cb][q];
                }
            }
        }
}

// ---- CSR build ----
__global__ void k_hist(const int* __restrict__ col, int* __restrict__ cnt) {
    int e = blockIdx.x * blockDim.x + threadIdx.x;
    if (e < N_EDGES) atomicAdd(cnt + col[e], 1);
}

__global__ __launch_bounds__(256) void k_scanA(const int* __restrict__ cnt,
                                               int* __restrict__ excl,
                                               int* __restrict__ bsum) {
    __shared__ int s[256];
    int i = blockIdx.x * 256 + threadIdx.x;
    int v = (i < N_NODES) ? cnt[i] : 0;
    s[threadIdx.x] = v;
    __syncthreads();
#pragma unroll
    for (int off = 1; off < 256; off <<= 1) {
        int t = (threadIdx.x >= off) ? s[threadIdx.x - off] : 0;
        __syncthreads();
        s[threadIdx.x] += t;
        __syncthreads();
    }
    if (i < N_NODES) excl[i] = s[threadIdx.x] - v;
    if (threadIdx.x == 255) bsum[blockIdx.x] = s[255];
}

__global__ __launch_bounds__(256) void k_scanB(int* __restrict__ bsum) {
    __shared__ int s[256];
    int v = (threadIdx.x < NB_SCAN) ? bsum[threadIdx.x] : 0;
    s[threadIdx.x] = v;
    __syncthreads();
#pragma unroll
    for (int off = 1; off < 256; off <<= 1) {
        int t = (threadIdx.x >= off) ? s[threadIdx.x - off] : 0;
        __syncthreads();
        s[threadIdx.x] += t;
        __syncthreads();
    }
    bsum[threadIdx.x] = s[threadIdx.x] - v;
}

__global__ __launch_bounds__(256) void k_scanC(int* __restrict__ ptr,
                                               int* __restrict__ cursor,
                                               const int* __restrict__ bsum) {
    int i = blockIdx.x * 256 + threadIdx.x;
    if (i >= N_NODES) return;
    int p = ptr[i] + bsum[blockIdx.x];
    ptr[i] = p;
    cursor[i] = p;
}

__global__ void k_scatter(const int* __restrict__ row, const int* __restrict__ col,
                          int* __restrict__ cursor, int* __restrict__ spay) {
    int e = blockIdx.x * blockDim.x + threadIdx.x;
    if (e >= N_EDGES) return;
    int c = col[e];
    int pos = atomicAdd(cursor + c, 1);
    spay[pos] = row[e] | ((e / EPR) << 20);
}

// pull-aggregation, bf16 feat gather, 4-deep explicit pipeline
__global__ __launch_bounds__(256) void k_agg(const int* __restrict__ ptr,
                                             const int* __restrict__ cnt,
                                             const int* __restrict__ spay,
                                             const float* __restrict__ el,
                                             const float* __restrict__ er,
                                             const __bf16* __restrict__ featb,
                                             const float* __restrict__ bias,
                                             float* __restrict__ out) {
    const int wv = threadIdx.x >> 6, lane = threadIdx.x & 63;
    const int n = blockIdx.x * 4 + wv;
    if (n >= N_NODES) return;
    const int start = ptr[n], len = cnt[n];
    const int h = lane >> 4;
    float accx = 0.f, accy = 0.f, den = 0.f;
    int j = 0;
    for (; j + 4 <= len; j += 4) {
        int p[4];
#pragma unroll
        for (int u = 0; u < 4; ++u) p[u] = spay[start + j + u];
        float w[4], vx[4], vy[4];
#pragma unroll
        for (int u = 0; u < 4; ++u) {
            int rw = p[u] & 0xFFFFF, r = p[u] >> 20;
            size_t rb = (size_t)r * N_NODES;
            float s = el[(rb + rw) * N_HEADS + h] + er[(rb + n) * N_HEADS + h];
            s = s > 0.f ? s : 0.2f * s;
            w[u] = __expf(s);
            ushort2 raw = *(const ushort2*)(featb + (rb + rw) * OUT_FEAT + lane * 2);
            vx[u] = __uint_as_float((unsigned)raw.x << 16);
            vy[u] = __uint_as_float((unsigned)raw.y << 16);
        }
#pragma unroll
        for (int u = 0; u < 4; ++u) {
            accx += w[u] * vx[u];
            accy += w[u] * vy[u];
            den += w[u];
        }
    }
    for (; j < len; ++j) {
        int p = spay[start + j];
        int rw = p & 0xFFFFF, r = p >> 20;
        size_t rb = (size_t)r * N_NODES;
        float s = el[(rb + rw) * N_HEADS + h] + er[(rb + n) * N_HEADS + h];
        s = s > 0.f ? s : 0.2f * s;
        float w = __expf(s);
        ushort2 raw = *(const ushort2*)(featb + (rb + rw) * OUT_FEAT + lane * 2);
        accx += w * __uint_as_float((unsigned)raw.x << 16);
        accy += w * __uint_as_float((unsigned)raw.y << 16);
        den += w;
    }
    float inv = (len > 0) ? 1.f / den : 0.f;
    int o = lane * 2;
    float2 res;
    res.x = accx * inv + bias[o];
    res.y = accy * inv + bias[o + 1];
    *(float2*)(out + (size_t)n * OUT_FEAT + o) = res;
}

extern "C" void kernel_launch(void* const* d_in, const int* in_sizes, int n_in,
                              void* d_out, int out_size, void* d_ws, size_t ws_size,
                              hipStream_t stream) {
    const float* x = (const float*)d_in[0];
    const float* cw = (const float*)d_in[1];
    const float* al = (const float*)d_in[2];
    const float* ar = (const float*)d_in[3];
    const float* bias = (const float*)d_in[4];
    const int* row = (const int*)d_in[5];
    const int* col = (const int*)d_in[6];
    float* out = (float*)d_out;
    float* ws = (float*)d_ws;

    __bf16* featb = (__bf16*)(ws + OFF_FEAT);
    float* el = ws + OFF_EL;
    float* er = ws + OFF_ER;
    __bf16* wbt = (__bf16*)(ws + OFF_WB);
    __bf16* wbg = (__bf16*)(ws + OFF_WB + 8192);
    __bf16* wtg = (__bf16*)(ws + OFF_WT);
    int* iw = (int*)(ws + OFF_INT);
    int* cnt = iw + IOFF_CNT;
    int* ptr = iw + IOFF_PTR;
    int* cur = iw + IOFF_CUR;
    int* bsum = iw + IOFF_BSUM;
    int* spay = iw + IOFF_SPAY;

    hipMemsetAsync(cnt, 0, N_NODES * sizeof(int), stream);

    k_cvtw<<<128, 256, 0, stream>>>(cw, wtg);
    k_wboth<<<(IN_FEAT * 64 + 255) / 256, 256, 0, stream>>>(cw, al, ar, wbt);
    k_wbg<<<8, 256, 0, stream>>>(wbt, wbg);
    k_fused<<<(N_NODES + 63) / 64, 256, 0, stream>>>(x, wtg, wbg, featb, el, er);

    k_hist<<<(N_EDGES + 255) / 256, 256, 0, stream>>>(col, cnt);
    k_scanA<<<NB_SCAN, 256, 0, stream>>>(cnt, ptr, bsum);
    k_scanB<<<1, 256, 0, stream>>>(bsum);
    k_scanC<<<NB_SCAN, 256, 0, stream>>>(ptr, cur, bsum);
    k_scatter<<<(N_EDGES + 255) / 256, 256, 0, stream>>>(row, col, cur, spay);

    k_agg<<<(N_NODES + 3) / 4, 256, 0, stream>>>(ptr, cnt, spay, el, er, featb, bias, out);
}

// Round 12
// 257.985 us; speedup vs baseline: 1.2477x; 1.0073x over previous
//
#include <hip/hip_runtime.h>
#include <hip/hip_bf16.h>

#define N_NODES 50000
#define N_EDGES 819200
#define NUM_RELS 8
#define EPR (N_EDGES / NUM_RELS) /* 102400 */
#define N_HEADS 4
#define IN_FEAT 256
#define OUT_FEAT 128
#define HEAD_DIM 32
#define NB_SCAN ((N_NODES + 255) / 256) /* 196 */

typedef __attribute__((ext_vector_type(8))) __bf16 bf16x8;
typedef __attribute__((ext_vector_type(4))) __bf16 bf16x4;
typedef __attribute__((ext_vector_type(4))) float f32x4;

// ---- workspace layout (float units) ----
#define SZ_FEAT ((size_t)NUM_RELS * N_NODES * OUT_FEAT)
#define SZ_EL ((size_t)NUM_RELS * N_NODES * N_HEADS)
#define SZ_WB ((size_t)IN_FEAT * 64) /* wbt bf16 (32KB) */
#define SZ_WT ((size_t)NUM_RELS * OUT_FEAT * IN_FEAT / 2)
#define OFF_FEAT ((size_t)0)
#define OFF_EL (OFF_FEAT + SZ_FEAT)
#define OFF_ER (OFF_EL + SZ_EL)
#define OFF_WB (OFF_ER + SZ_EL)
#define OFF_WT (OFF_WB + SZ_WB)
#define OFF_INT (OFF_WT + SZ_WT)
#define IOFF_CNT ((size_t)0)
#define IOFF_PTR ((size_t)N_NODES)
#define IOFF_CUR ((size_t)2 * N_NODES)
#define IOFF_BSUM ((size_t)3 * N_NODES)
#define IOFF_SPAY ((size_t)3 * N_NODES + 256)

// folded attention vectors, transposed bf16: wbt[col][k], col = side*32+r*4+h
__global__ void k_wboth(const float* __restrict__ cw, const float* __restrict__ al,
                        const float* __restrict__ ar, __bf16* __restrict__ wbt) {
    int tid = blockIdx.x * blockDim.x + threadIdx.x;
    if (tid >= IN_FEAT * 64) return;
    int col = tid >> 8, i = tid & 255;
    int side = col >> 5, r = (col >> 2) & 7, h = col & 3;
    const float* av = (side ? ar : al) + (size_t)(r * N_HEADS + h) * HEAD_DIM;
    const float* cwp = cw + ((size_t)(r * N_HEADS + h) * IN_FEAT + i) * HEAD_DIM;
    float s = 0.f;
#pragma unroll
    for (int d = 0; d < HEAD_DIM; ++d) s += cwp[d] * av[d];
    wbt[(size_t)col * IN_FEAT + i] = (__bf16)s;
}

// wt[r][o][k] = bf16(cw[r][h][k][d]), o = h*32+d  -> B-operand k-contiguous
__global__ void k_cvt_w(const float* __restrict__ cw, __bf16* __restrict__ wt) {
    int tid = blockIdx.x * blockDim.x + threadIdx.x;
    if (tid >= NUM_RELS * N_HEADS * IN_FEAT * HEAD_DIM) return;
    int d = tid & 31, k = (tid >> 5) & 255, h = (tid >> 13) & 3, r = tid >> 15;
    float v = cw[tid];
    wt[((size_t)(r * OUT_FEAT + h * HEAD_DIM + d)) * IN_FEAT + k] = (__bf16)v;
}

// Fused transform (R6 structure + T14 async-stage split):
// A staged once (128 rows x 256 k bf16, swizzled); 32 GEMM chunks (r,kc) with
// B prefetched global->regs during previous chunk's compute, ds_write after
// the post-compute barrier; then 4 el/er chunks the same way.
__global__ __launch_bounds__(256) void k_fused(const float* __restrict__ x,
                                               const __bf16* __restrict__ wt,
                                               const __bf16* __restrict__ wbt,
                                               __bf16* __restrict__ featb,
                                               float* __restrict__ el,
                                               float* __restrict__ er) {
    __shared__ __align__(16) unsigned char sA[65536]; // [128 rows][512B] swizzled
    __shared__ __align__(16) unsigned char sB[16384]; // one 16KB B chunk
    const int t = threadIdx.x;
    const int lane = t & 63;
    const int w = t >> 6;
    const int wr = w >> 1, wc = w & 1;
    const int n0 = blockIdx.x * 128;

    // ---- issue B chunk 0 loads first (hide under A staging) ----
    bf16x8 breg0, breg1, breg2, breg3;
    {
        const __bf16* wtr = wt; // r=0, kc=0
#pragma unroll
        for (int i = 0; i < 4; ++i) {
            int flat = i * 256 + t;
            int brow = flat >> 3, s = flat & 7, ssrc = s ^ (brow & 7);
            bf16x8 v = *(const bf16x8*)(wtr + (size_t)brow * IN_FEAT + ssrc * 8);
            if (i == 0) breg0 = v; else if (i == 1) breg1 = v; else if (i == 2) breg2 = v; else breg3 = v;
        }
    }

    // ---- stage A once: 128 rows x 256 k, fp32 -> bf16, swizzled ----
#pragma unroll 8
    for (int i = 0; i < 32; ++i) {
        int flat = i * 256 + t;       // float4 units
        int row = flat >> 6;          // 0..127
        int kq = flat & 63;           // k = kq*4
        int n = n0 + row;
        if (n >= N_NODES) n = N_NODES - 1;
        float4 v = *(const float4*)(x + (size_t)n * IN_FEAT + kq * 4);
        bf16x4 hv;
        hv[0] = (__bf16)v.x; hv[1] = (__bf16)v.y; hv[2] = (__bf16)v.z; hv[3] = (__bf16)v.w;
        int sg = kq >> 1;
        int slot = (sg & ~7) | ((sg & 7) ^ (row & 7));
        *(bf16x4*)(sA + row * 512 + slot * 16 + (kq & 1) * 8) = hv;
    }

    f32x4 acc[4][4];
#pragma unroll
    for (int i = 0; i < 4; ++i)
#pragma unroll
        for (int j = 0; j < 4; ++j) acc[i][j] = (f32x4){0.f, 0.f, 0.f, 0.f};

    bf16x8 wbreg0, wbreg1;

    // ---- 32 GEMM chunks (idx = r*4 + kc) ----
    for (int idx = 0; idx < 32; ++idx) {
        // write prefetched chunk to sB (compiler inserts vmcnt wait)
#pragma unroll
        for (int i = 0; i < 4; ++i) {
            int flat = i * 256 + t;
            int brow = flat >> 3, s = flat & 7;
            bf16x8 v = (i == 0) ? breg0 : (i == 1) ? breg1 : (i == 2) ? breg2 : breg3;
            *(bf16x8*)(sB + brow * 128 + s * 16) = v;
        }
        __syncthreads(); // sB (and, at idx 0, sA) ready

        // issue next chunk's loads NOW — latency hides under compute below
        if (idx < 31) {
            const __bf16* wtr = wt + (size_t)((idx + 1) >> 2) * OUT_FEAT * IN_FEAT;
            int kc_n = (idx + 1) & 3;
#pragma unroll
            for (int i = 0; i < 4; ++i) {
                int flat = i * 256 + t;
                int brow = flat >> 3, s = flat & 7, ssrc = s ^ (brow & 7);
                bf16x8 v = *(const bf16x8*)(wtr + (size_t)brow * IN_FEAT + kc_n * 64 + ssrc * 8);
                if (i == 0) breg0 = v; else if (i == 1) breg1 = v; else if (i == 2) breg2 = v; else breg3 = v;
            }
        } else { // prefetch first el/er chunk (kc=0)
#pragma unroll
            for (int i = 0; i < 2; ++i) {
                int flat = i * 256 + t;
                int brow = flat >> 3, s = flat & 7, ssrc = s ^ (brow & 7);
                bf16x8 v = *(const bf16x8*)(wbt + (size_t)brow * IN_FEAT + ssrc * 8);
                if (i == 0) wbreg0 = v; else wbreg1 = v;
            }
        }

        const int r = idx >> 2, kc = idx & 3;
#pragma unroll
        for (int ks = 0; ks < 2; ++ks) {
            bf16x8 af[4], bg[4];
#pragma unroll
            for (int rb = 0; rb < 4; ++rb) {
                int row = wr * 64 + rb * 16 + (lane & 15);
                int slot = kc * 8 + ((ks * 4 + (lane >> 4)) ^ (row & 7));
                af[rb] = *(const bf16x8*)(sA + row * 512 + slot * 16);
            }
#pragma unroll
            for (int cb = 0; cb < 4; ++cb) {
                int brow = wc * 64 + cb * 16 + (lane & 15);
                int slot = (ks * 4 + (lane >> 4)) ^ (brow & 7);
                bg[cb] = *(const bf16x8*)(sB + brow * 128 + slot * 16);
            }
#pragma unroll
            for (int rb = 0; rb < 4; ++rb)
#pragma unroll
                for (int cb = 0; cb < 4; ++cb)
                    acc[rb][cb] = __builtin_amdgcn_mfma_f32_16x16x32_bf16(af[rb], bg[cb], acc[rb][cb], 0, 0, 0);
        }

        if (kc == 3) { // epilogue rel r (C map: col=lane&15, row=(lane>>4)*4+q)
#pragma unroll
            for (int rb = 0; rb < 4; ++rb)
#pragma unroll
                for (int q = 0; q < 4; ++q) {
                    int rowi = wr * 64 + rb * 16 + (lane >> 4) * 4 + q;
                    int n = n0 + rowi;
                    if (n < N_NODES) {
                        __bf16* fp = featb + ((size_t)r * N_NODES + n) * OUT_FEAT + wc * 64 + (lane & 15);
#pragma unroll
                        for (int cb = 0; cb < 4; ++cb) fp[cb * 16] = (__bf16)acc[rb][cb][q];
                    }
                }
#pragma unroll
            for (int i = 0; i < 4; ++i)
#pragma unroll
                for (int j = 0; j < 4; ++j) acc[i][j] = (f32x4){0.f, 0.f, 0.f, 0.f};
        }
        __syncthreads(); // all reads of sB done before next overwrite
    }

    // ---- el/er pass: 4 chunks of wbt [64 cols][64 k] ----
    f32x4 acc2[4][2];
#pragma unroll
    for (int i = 0; i < 4; ++i)
#pragma unroll
        for (int j = 0; j < 2; ++j) acc2[i][j] = (f32x4){0.f, 0.f, 0.f, 0.f};

    for (int kc = 0; kc < 4; ++kc) {
#pragma unroll
        for (int i = 0; i < 2; ++i) {
            int flat = i * 256 + t;
            int brow = flat >> 3, s = flat & 7;
            *(bf16x8*)(sB + brow * 128 + s * 16) = (i == 0) ? wbreg0 : wbreg1;
        }
        __syncthreads();
        if (kc < 3) {
            int kc_n = kc + 1;
#pragma unroll
            for (int i = 0; i < 2; ++i) {
                int flat = i * 256 + t;
                int brow = flat >> 3, s = flat & 7, ssrc = s ^ (brow & 7);
                bf16x8 v = *(const bf16x8*)(wbt + (size_t)brow * IN_FEAT + kc_n * 64 + ssrc * 8);
                if (i == 0) wbreg0 = v; else wbreg1 = v;
            }
        }
#pragma unroll
        for (int ks = 0; ks < 2; ++ks) {
            bf16x8 af[4], bg[2];
#pragma unroll
            for (int rb = 0; rb < 4; ++rb) {
                int row = wr * 64 + rb * 16 + (lane & 15);
                int slot = kc * 8 + ((ks * 4 + (lane >> 4)) ^ (row & 7));
                af[rb] = *(const bf16x8*)(sA + row * 512 + slot * 16);
            }
#pragma unroll
            for (int cb = 0; cb < 2; ++cb) {
                int brow = wc * 32 + cb * 16 + (lane & 15);
                int slot = (ks * 4 + (lane >> 4)) ^ (brow & 7);
                bg[cb] = *(const bf16x8*)(sB + brow * 128 + slot * 16);
            }
#pragma unroll
            for (int rb = 0; rb < 4; ++rb)
#pragma unroll
                for (int cb = 0; cb < 2; ++cb)
                    acc2[rb][cb] = __builtin_amdgcn_mfma_f32_16x16x32_bf16(af[rb], bg[cb], acc2[rb][cb], 0, 0, 0);
        }
        __syncthreads();
    }
#pragma unroll
    for (int rb = 0; rb < 4; ++rb)
#pragma unroll
        for (int q = 0; q < 4; ++q) {
            int n = n0 + wr * 64 + rb * 16 + (lane >> 4) * 4 + q;
            if (n < N_NODES) {
#pragma unroll
                for (int cb = 0; cb < 2; ++cb) {
                    int c = wc * 32 + cb * 16 + (lane & 15);
                    int side = c >> 5, rr = (c >> 2) & 7, h = c & 3;
                    float* dst = side ? er : el;
                    dst[((size_t)rr * N_NODES + n) * N_HEADS + h] = acc2[rb][cb][q];
                }
            }
        }
}

// ---- CSR build ----
__global__ void k_hist(const int* __restrict__ col, int* __restrict__ cnt) {
    int e = blockIdx.x * blockDim.x + threadIdx.x;
    if (e < N_EDGES) atomicAdd(cnt + col[e], 1);
}

__global__ __launch_bounds__(256) void k_scanA(const int* __restrict__ cnt,
                                               int* __restrict__ excl,
                                               int* __restrict__ bsum) {
    __shared__ int s[256];
    int i = blockIdx.x * 256 + threadIdx.x;
    int v = (i < N_NODES) ? cnt[i] : 0;
    s[threadIdx.x] = v;
    __syncthreads();
#pragma unroll
    for (int off = 1; off < 256; off <<= 1) {
        int t = (threadIdx.x >= off) ? s[threadIdx.x - off] : 0;
        __syncthreads();
        s[threadIdx.x] += t;
        __syncthreads();
    }
    if (i < N_NODES) excl[i] = s[threadIdx.x] - v;
    if (threadIdx.x == 255) bsum[blockIdx.x] = s[255];
}

__global__ __launch_bounds__(256) void k_scanB(int* __restrict__ bsum) {
    __shared__ int s[256];
    int v = (threadIdx.x < NB_SCAN) ? bsum[threadIdx.x] : 0;
    s[threadIdx.x] = v;
    __syncthreads();
#pragma unroll
    for (int off = 1; off < 256; off <<= 1) {
        int t = (threadIdx.x >= off) ? s[threadIdx.x - off] : 0;
        __syncthreads();
        s[threadIdx.x] += t;
        __syncthreads();
    }
    bsum[threadIdx.x] = s[threadIdx.x] - v;
}

__global__ __launch_bounds__(256) void k_scanC(int* __restrict__ ptr,
                                               int* __restrict__ cursor,
                                               const int* __restrict__ bsum) {
    int i = blockIdx.x * 256 + threadIdx.x;
    if (i >= N_NODES) return;
    int p = ptr[i] + bsum[blockIdx.x];
    ptr[i] = p;
    cursor[i] = p;
}

__global__ void k_scatter(const int* __restrict__ row, const int* __restrict__ col,
                          int* __restrict__ cursor, int* __restrict__ spay) {
    int e = blockIdx.x * blockDim.x + threadIdx.x;
    if (e >= N_EDGES) return;
    int c = col[e];
    int pos = atomicAdd(cursor + c, 1);
    spay[pos] = row[e] | ((e / EPR) << 20);
}

// pull-aggregation, bf16 feat gather, 4-deep explicit pipeline
__global__ __launch_bounds__(256) void k_agg(const int* __restrict__ ptr,
                                             const int* __restrict__ cnt,
                                             const int* __restrict__ spay,
                                             const float* __restrict__ el,
                                             const float* __restrict__ er,
                                             const __bf16* __restrict__ featb,
                                             const float* __restrict__ bias,
                                             float* __restrict__ out) {
    const int wv = threadIdx.x >> 6, lane = threadIdx.x & 63;
    const int n = blockIdx.x * 4 + wv;
    if (n >= N_NODES) return;
    const int start = ptr[n], len = cnt[n];
    const int h = lane >> 4;
    float accx = 0.f, accy = 0.f, den = 0.f;
    int j = 0;
    for (; j + 4 <= len; j += 4) {
        int p[4];
#pragma unroll
        for (int u = 0; u < 4; ++u) p[u] = spay[start + j + u];
        float w[4], vx[4], vy[4];
#pragma unroll
        for (int u = 0; u < 4; ++u) {
            int rw = p[u] & 0xFFFFF, r = p[u] >> 20;
            size_t rb = (size_t)r * N_NODES;
            float s = el[(rb + rw) * N_HEADS + h] + er[(rb + n) * N_HEADS + h];
            s = s > 0.f ? s : 0.2f * s;
            w[u] = __expf(s);
            ushort2 raw = *(const ushort2*)(featb + (rb + rw) * OUT_FEAT + lane * 2);
            vx[u] = __uint_as_float((unsigned)raw.x << 16);
            vy[u] = __uint_as_float((unsigned)raw.y << 16);
        }
#pragma unroll
        for (int u = 0; u < 4; ++u) {
            accx += w[u] * vx[u];
            accy += w[u] * vy[u];
            den += w[u];
        }
    }
    for (; j < len; ++j) {
        int p = spay[start + j];
        int rw = p & 0xFFFFF, r = p >> 20;
        size_t rb = (size_t)r * N_NODES;
        float s = el[(rb + rw) * N_HEADS + h] + er[(rb + n) * N_HEADS + h];
        s = s > 0.f ? s : 0.2f * s;
        float w = __expf(s);
        ushort2 raw = *(const ushort2*)(featb + (rb + rw) * OUT_FEAT + lane * 2);
        accx += w * __uint_as_float((unsigned)raw.x << 16);
        accy += w * __uint_as_float((unsigned)raw.y << 16);
        den += w;
    }
    float inv = (len > 0) ? 1.f / den : 0.f;
    int o = lane * 2;
    float2 res;
    res.x = accx * inv + bias[o];
    res.y = accy * inv + bias[o + 1];
    *(float2*)(out + (size_t)n * OUT_FEAT + o) = res;
}

extern "C" void kernel_launch(void* const* d_in, const int* in_sizes, int n_in,
                              void* d_out, int out_size, void* d_ws, size_t ws_size,
                              hipStream_t stream) {
    const float* x = (const float*)d_in[0];
    const float* cw = (const float*)d_in[1];
    const float* al = (const float*)d_in[2];
    const float* ar = (const float*)d_in[3];
    const float* bias = (const float*)d_in[4];
    const int* row = (const int*)d_in[5];
    const int* col = (const int*)d_in[6];
    float* out = (float*)d_out;
    float* ws = (float*)d_ws;

    __bf16* featb = (__bf16*)(ws + OFF_FEAT);
    float* el = ws + OFF_EL;
    float* er = ws + OFF_ER;
    __bf16* wbt = (__bf16*)(ws + OFF_WB);
    __bf16* wt = (__bf16*)(ws + OFF_WT);
    int* iw = (int*)(ws + OFF_INT);
    int* cnt = iw + IOFF_CNT;
    int* ptr = iw + IOFF_PTR;
    int* cur = iw + IOFF_CUR;
    int* bsum = iw + IOFF_BSUM;
    int* spay = iw + IOFF_SPAY;

    hipMemsetAsync(cnt, 0, N_NODES * sizeof(int), stream);

    k_wboth<<<(IN_FEAT * 64 + 255) / 256, 256, 0, stream>>>(cw, al, ar, wbt);
    k_cvt_w<<<(NUM_RELS * N_HEADS * IN_FEAT * HEAD_DIM + 255) / 256, 256, 0, stream>>>(cw, wt);
    k_fused<<<(N_NODES + 127) / 128, 256, 0, stream>>>(x, wt, wbt, featb, el, er);

    k_hist<<<(N_EDGES + 255) / 256, 256, 0, stream>>>(col, cnt);
    k_scanA<<<NB_SCAN, 256, 0, stream>>>(cnt, ptr, bsum);
    k_scanB<<<1, 256, 0, stream>>>(bsum);
    k_scanC<<<NB_SCAN, 256, 0, stream>>>(ptr, cur, bsum);
    k_scatter<<<(N_EDGES + 255) / 256, 256, 0, stream>>>(row, col, cur, spay);

    k_agg<<<(N_NODES + 3) / 4, 256, 0, stream>>>(ptr, cnt, spay, el, er, featb, bias, out);
}

// Round 13
// 238.721 us; speedup vs baseline: 1.3483x; 1.0807x over previous
//
#include <hip/hip_runtime.h>
#include <hip/hip_bf16.h>

#define N_NODES 50000
#define N_EDGES 819200
#define NUM_RELS 8
#define EPR (N_EDGES / NUM_RELS) /* 102400 */
#define N_HEADS 4
#define IN_FEAT 256
#define OUT_FEAT 128
#define HEAD_DIM 32
#define NB_SCAN ((N_NODES + 255) / 256) /* 196 */

typedef __attribute__((ext_vector_type(8))) __bf16 bf16x8;
typedef __attribute__((ext_vector_type(4))) __bf16 bf16x4;
typedef __attribute__((ext_vector_type(4))) float f32x4;

// ---- workspace layout (float units) ----
#define SZ_FEAT ((size_t)NUM_RELS * N_NODES * OUT_FEAT)
#define SZ_EL ((size_t)NUM_RELS * N_NODES * N_HEADS)
#define SZ_WB ((size_t)IN_FEAT * 64)
#define SZ_WT ((size_t)NUM_RELS * OUT_FEAT * IN_FEAT / 2)
#define OFF_FEAT ((size_t)0)
#define OFF_EL (OFF_FEAT + SZ_FEAT)
#define OFF_ER (OFF_EL + SZ_EL)
#define OFF_WB (OFF_ER + SZ_EL)
#define OFF_WT (OFF_WB + SZ_WB)
#define OFF_INT (OFF_WT + SZ_WT)
#define IOFF_CNT ((size_t)0)
#define IOFF_PTR ((size_t)N_NODES)
#define IOFF_CUR ((size_t)2 * N_NODES)
#define IOFF_BSUM ((size_t)3 * N_NODES)
#define IOFF_SPAY ((size_t)3 * N_NODES + 256)

// folded attention vectors, transposed bf16: wbt[col][k], col = side*32+r*4+h
__global__ void k_wboth(const float* __restrict__ cw, const float* __restrict__ al,
                        const float* __restrict__ ar, __bf16* __restrict__ wbt) {
    int tid = blockIdx.x * blockDim.x + threadIdx.x;
    if (tid >= IN_FEAT * 64) return;
    int col = tid >> 8, i = tid & 255;
    int side = col >> 5, r = (col >> 2) & 7, h = col & 3;
    const float* av = (side ? ar : al) + (size_t)(r * N_HEADS + h) * HEAD_DIM;
    const float* cwp = cw + ((size_t)(r * N_HEADS + h) * IN_FEAT + i) * HEAD_DIM;
    float s = 0.f;
#pragma unroll
    for (int d = 0; d < HEAD_DIM; ++d) s += cwp[d] * av[d];
    wbt[(size_t)col * IN_FEAT + i] = (__bf16)s;
}

// wt[r][o][k] = bf16(cw[r][h][k][d]), o = h*32+d
__global__ void k_cvt_w(const float* __restrict__ cw, __bf16* __restrict__ wt) {
    int tid = blockIdx.x * blockDim.x + threadIdx.x;
    if (tid >= NUM_RELS * N_HEADS * IN_FEAT * HEAD_DIM) return;
    int d = tid & 31, k = (tid >> 5) & 255, h = (tid >> 13) & 3, r = tid >> 15;
    float v = cw[tid];
    wt[((size_t)(r * OUT_FEAT + h * HEAD_DIM + d)) * IN_FEAT + k] = (__bf16)v;
}

// Fused (R6-proven): X staged once per 128-node tile (full K=256 bf16, swizzled),
// then 8 rel GEMM passes (feat) + 1 folded-attn pass (el/er). 4 waves as 2x2.
__global__ __launch_bounds__(256) void k_fused(const float* __restrict__ x,
                                               const __bf16* __restrict__ wt,
                                               const __bf16* __restrict__ wbt,
                                               __bf16* __restrict__ featb,
                                               float* __restrict__ el,
                                               float* __restrict__ er) {
    __shared__ __align__(16) unsigned char sA[65536]; // [128 rows][512B] swizzled
    __shared__ __align__(16) unsigned char sB[16384]; // [128 rows][128B] swizzled
    const int t = threadIdx.x;
    const int lane = t & 63;
    const int w = t >> 6;
    const int wr = w >> 1, wc = w & 1;
    const int n0 = blockIdx.x * 128;

    // ---- stage A once: 128 rows x 256 k, fp32 -> bf16, swizzled ----
#pragma unroll 8
    for (int i = 0; i < 32; ++i) {
        int flat = i * 256 + t;
        int row = flat >> 6;
        int kq = flat & 63;
        int n = n0 + row;
        if (n >= N_NODES) n = N_NODES - 1;
        float4 v = *(const float4*)(x + (size_t)n * IN_FEAT + kq * 4);
        bf16x4 hv;
        hv[0] = (__bf16)v.x; hv[1] = (__bf16)v.y; hv[2] = (__bf16)v.z; hv[3] = (__bf16)v.w;
        int sg = kq >> 1;
        int slot = (sg & ~7) | ((sg & 7) ^ (row & 7));
        *(bf16x4*)(sA + row * 512 + slot * 16 + (kq & 1) * 8) = hv;
    }
    __syncthreads();

    f32x4 acc[4][4];

    // ---- 8 relation passes ----
    for (int r = 0; r < NUM_RELS; ++r) {
#pragma unroll
        for (int i = 0; i < 4; ++i)
#pragma unroll
            for (int j = 0; j < 4; ++j) acc[i][j] = (f32x4){0.f, 0.f, 0.f, 0.f};
        const __bf16* wtr = wt + (size_t)r * OUT_FEAT * IN_FEAT;

        for (int kc = 0; kc < 4; ++kc) {
#pragma unroll
            for (int i = 0; i < 4; ++i) {
                int flat = i * 256 + t;
                int brow = flat >> 3;
                int s = flat & 7;
                int ssrc = s ^ (brow & 7);
                bf16x8 v = *(const bf16x8*)(wtr + (size_t)brow * IN_FEAT + kc * 64 + ssrc * 8);
                *(bf16x8*)(sB + brow * 128 + s * 16) = v;
            }
            __syncthreads();
#pragma unroll
            for (int ks = 0; ks < 2; ++ks) {
                bf16x8 af[4], bg[4];
#pragma unroll
                for (int rb = 0; rb < 4; ++rb) {
                    int row = wr * 64 + rb * 16 + (lane & 15);
                    int slot = kc * 8 + ((ks * 4 + (lane >> 4)) ^ (row & 7));
                    af[rb] = *(const bf16x8*)(sA + row * 512 + slot * 16);
                }
#pragma unroll
                for (int cb = 0; cb < 4; ++cb) {
                    int brow = wc * 64 + cb * 16 + (lane & 15);
                    int slot = (ks * 4 + (lane >> 4)) ^ (brow & 7);
                    bg[cb] = *(const bf16x8*)(sB + brow * 128 + slot * 16);
                }
#pragma unroll
                for (int rb = 0; rb < 4; ++rb)
#pragma unroll
                    for (int cb = 0; cb < 4; ++cb)
                        acc[rb][cb] = __builtin_amdgcn_mfma_f32_16x16x32_bf16(af[rb], bg[cb], acc[rb][cb], 0, 0, 0);
            }
            __syncthreads();
        }
        // epilogue rel r (C map: col=lane&15, row=(lane>>4)*4+q)
#pragma unroll
        for (int rb = 0; rb < 4; ++rb) {
#pragma unroll
            for (int q = 0; q < 4; ++q) {
                int row = wr * 64 + rb * 16 + (lane >> 4) * 4 + q;
                int n = n0 + row;
                if (n < N_NODES) {
                    __bf16* fp = featb + ((size_t)r * N_NODES + n) * OUT_FEAT + wc * 64 + (lane & 15);
#pragma unroll
                    for (int cb = 0; cb < 4; ++cb) fp[cb * 16] = (__bf16)acc[rb][cb][q];
                }
            }
        }
    }

    // ---- el/er pass: B = wbt[64 cols][256 k]; waves tile 128 rows x 64 cols ----
#pragma unroll
    for (int i = 0; i < 4; ++i)
#pragma unroll
        for (int j = 0; j < 2; ++j) acc[i][j] = (f32x4){0.f, 0.f, 0.f, 0.f};

    for (int kc = 0; kc < 4; ++kc) {
#pragma unroll
        for (int i = 0; i < 2; ++i) {
            int flat = i * 256 + t;
            int brow = flat >> 3;
            int s = flat & 7;
            int ssrc = s ^ (brow & 7);
            bf16x8 v = *(const bf16x8*)(wbt + (size_t)brow * IN_FEAT + kc * 64 + ssrc * 8);
            *(bf16x8*)(sB + brow * 128 + s * 16) = v;
        }
        __syncthreads();
#pragma unroll
        for (int ks = 0; ks < 2; ++ks) {
            bf16x8 af[4], bg[2];
#pragma unroll
            for (int rb = 0; rb < 4; ++rb) {
                int row = wr * 64 + rb * 16 + (lane & 15);
                int slot = kc * 8 + ((ks * 4 + (lane >> 4)) ^ (row & 7));
                af[rb] = *(const bf16x8*)(sA + row * 512 + slot * 16);
            }
#pragma unroll
            for (int cb = 0; cb < 2; ++cb) {
                int brow = wc * 32 + cb * 16 + (lane & 15);
                int slot = (ks * 4 + (lane >> 4)) ^ (brow & 7);
                bg[cb] = *(const bf16x8*)(sB + brow * 128 + slot * 16);
            }
#pragma unroll
            for (int rb = 0; rb < 4; ++rb)
#pragma unroll
                for (int cb = 0; cb < 2; ++cb)
                    acc[rb][cb] = __builtin_amdgcn_mfma_f32_16x16x32_bf16(af[rb], bg[cb], acc[rb][cb], 0, 0, 0);
        }
        __syncthreads();
    }
#pragma unroll
    for (int rb = 0; rb < 4; ++rb) {
#pragma unroll
        for (int q = 0; q < 4; ++q) {
            int n = n0 + wr * 64 + rb * 16 + (lane >> 4) * 4 + q;
            if (n < N_NODES) {
#pragma unroll
                for (int cb = 0; cb < 2; ++cb) {
                    int c = wc * 32 + cb * 16 + (lane & 15);
                    int side = c >> 5, rr = (c >> 2) & 7, h = c & 3;
                    float* dst = side ? er : el;
                    dst[((size_t)rr * N_NODES + n) * N_HEADS + h] = acc[rb][cb][q];
                }
            }
        }
    }
}

// ---- CSR build ----
__global__ void k_hist(const int* __restrict__ col, int* __restrict__ cnt) {
    int e = blockIdx.x * blockDim.x + threadIdx.x;
    if (e < N_EDGES) atomicAdd(cnt + col[e], 1);
}

__global__ __launch_bounds__(256) void k_scanA(const int* __restrict__ cnt,
                                               int* __restrict__ excl,
                                               int* __restrict__ bsum) {
    __shared__ int s[256];
    int i = blockIdx.x * 256 + threadIdx.x;
    int v = (i < N_NODES) ? cnt[i] : 0;
    s[threadIdx.x] = v;
    __syncthreads();
#pragma unroll
    for (int off = 1; off < 256; off <<= 1) {
        int t = (threadIdx.x >= off) ? s[threadIdx.x - off] : 0;
        __syncthreads();
        s[threadIdx.x] += t;
        __syncthreads();
    }
    if (i < N_NODES) excl[i] = s[threadIdx.x] - v;
    if (threadIdx.x == 255) bsum[blockIdx.x] = s[255];
}

__global__ __launch_bounds__(256) void k_scanB(int* __restrict__ bsum) {
    __shared__ int s[256];
    int v = (threadIdx.x < NB_SCAN) ? bsum[threadIdx.x] : 0;
    s[threadIdx.x] = v;
    __syncthreads();
#pragma unroll
    for (int off = 1; off < 256; off <<= 1) {
        int t = (threadIdx.x >= off) ? s[threadIdx.x - off] : 0;
        __syncthreads();
        s[threadIdx.x] += t;
        __syncthreads();
    }
    bsum[threadIdx.x] = s[threadIdx.x] - v;
}

__global__ __launch_bounds__(256) void k_scanC(int* __restrict__ ptr,
                                               int* __restrict__ cursor,
                                               const int* __restrict__ bsum) {
    int i = blockIdx.x * 256 + threadIdx.x;
    if (i >= N_NODES) return;
    int p = ptr[i] + bsum[blockIdx.x];
    ptr[i] = p;
    cursor[i] = p;
}

__global__ void k_scatter(const int* __restrict__ row, const int* __restrict__ col,
                          int* __restrict__ cursor, int* __restrict__ spay) {
    int e = blockIdx.x * blockDim.x + threadIdx.x;
    if (e >= N_EDGES) return;
    int c = col[e];
    int pos = atomicAdd(cursor + c, 1);
    spay[pos] = row[e] | ((e / EPR) << 20);
}

// pull-aggregation v2: half-wave edge pairing (lanes 0-31 edge 2j, 32-63 edge
// 2j+1; 4 outs/lane via ushort4), er preloaded for all 8 rels; zero atomics.
__global__ __launch_bounds__(256) void k_agg(const int* __restrict__ ptr,
                                             const int* __restrict__ cnt,
                                             const int* __restrict__ spay,
                                             const float* __restrict__ el,
                                             const float* __restrict__ er,
                                             const __bf16* __restrict__ featb,
                                             const float* __restrict__ bias,
                                             float* __restrict__ out) {
    const int wv = threadIdx.x >> 6, lane = threadIdx.x & 63;
    const int n = blockIdx.x * 4 + wv;
    if (n >= N_NODES) return;
    const int start = ptr[n], len = cnt[n];
    const int half = lane >> 5;
    const int hl = lane & 31;
    const int o0 = hl * 4;       // 4 outs per lane
    const int h = o0 >> 5;       // head (constant across the 4 outs)

    float er_r[8];
#pragma unroll
    for (int r = 0; r < 8; ++r)
        er_r[r] = er[((size_t)r * N_NODES + n) * N_HEADS + h];

    float a0 = 0.f, a1 = 0.f, a2 = 0.f, a3 = 0.f, den = 0.f;
    const int nit = (len + 1) >> 1;
#pragma unroll 2
    for (int j = 0; j < nit; ++j) {
        int idx = 2 * j + half;
        bool valid = idx < len;
        int p = valid ? spay[start + idx] : 0;
        int rw = p & 0xFFFFF, r = p >> 20;
        size_t rb = (size_t)r * N_NODES;
        float s = el[(rb + rw) * N_HEADS + h] + er_r[r];
        s = s > 0.f ? s : 0.2f * s;
        float wgt = valid ? __expf(s) : 0.f;
        ushort4 raw = *(const ushort4*)(featb + (rb + rw) * OUT_FEAT + o0);
        a0 += wgt * __uint_as_float((unsigned)raw.x << 16);
        a1 += wgt * __uint_as_float((unsigned)raw.y << 16);
        a2 += wgt * __uint_as_float((unsigned)raw.z << 16);
        a3 += wgt * __uint_as_float((unsigned)raw.w << 16);
        den += wgt;
    }
    // merge halves: lane L (<32) += lane L+32
    a0 += __shfl_down(a0, 32);
    a1 += __shfl_down(a1, 32);
    a2 += __shfl_down(a2, 32);
    a3 += __shfl_down(a3, 32);
    den += __shfl_down(den, 32);
    if (half == 0) {
        float inv = (len > 0) ? 1.f / den : 0.f;
        float4 res;
        res.x = a0 * inv + bias[o0];
        res.y = a1 * inv + bias[o0 + 1];
        res.z = a2 * inv + bias[o0 + 2];
        res.w = a3 * inv + bias[o0 + 3];
        *(float4*)(out + (size_t)n * OUT_FEAT + o0) = res;
    }
}

extern "C" void kernel_launch(void* const* d_in, const int* in_sizes, int n_in,
                              void* d_out, int out_size, void* d_ws, size_t ws_size,
                              hipStream_t stream) {
    const float* x = (const float*)d_in[0];
    const float* cw = (const float*)d_in[1];
    const float* al = (const float*)d_in[2];
    const float* ar = (const float*)d_in[3];
    const float* bias = (const float*)d_in[4];
    const int* row = (const int*)d_in[5];
    const int* col = (const int*)d_in[6];
    float* out = (float*)d_out;
    float* ws = (float*)d_ws;

    __bf16* featb = (__bf16*)(ws + OFF_FEAT);
    float* el = ws + OFF_EL;
    float* er = ws + OFF_ER;
    __bf16* wbt = (__bf16*)(ws + OFF_WB);
    __bf16* wt = (__bf16*)(ws + OFF_WT);
    int* iw = (int*)(ws + OFF_INT);
    int* cnt = iw + IOFF_CNT;
    int* ptr = iw + IOFF_PTR;
    int* cur = iw + IOFF_CUR;
    int* bsum = iw + IOFF_BSUM;
    int* spay = iw + IOFF_SPAY;

    hipMemsetAsync(cnt, 0, N_NODES * sizeof(int), stream);

    k_wboth<<<(IN_FEAT * 64 + 255) / 256, 256, 0, stream>>>(cw, al, ar, wbt);
    k_cvt_w<<<(NUM_RELS * N_HEADS * IN_FEAT * HEAD_DIM + 255) / 256, 256, 0, stream>>>(cw, wt);
    k_fused<<<(N_NODES + 127) / 128, 256, 0, stream>>>(x, wt, wbt, featb, el, er);

    k_hist<<<(N_EDGES + 255) / 256, 256, 0, stream>>>(col, cnt);
    k_scanA<<<NB_SCAN, 256, 0, stream>>>(cnt, ptr, bsum);
    k_scanB<<<1, 256, 0, stream>>>(bsum);
    k_scanC<<<NB_SCAN, 256, 0, stream>>>(ptr, cur, bsum);
    k_scatter<<<(N_EDGES + 255) / 256, 256, 0, stream>>>(row, col, cur, spay);

    k_agg<<<(N_NODES + 3) / 4, 256, 0, stream>>>(ptr, cnt, spay, el, er, featb, bias, out);
}

// Round 14
// 222.091 us; speedup vs baseline: 1.4493x; 1.0749x over previous
//
#include <hip/hip_runtime.h>
#include <hip/hip_bf16.h>

#define N_NODES 50000
#define N_EDGES 819200
#define NUM_RELS 8
#define EPR (N_EDGES / NUM_RELS) /* 102400 */
#define N_HEADS 4
#define IN_FEAT 256
#define OUT_FEAT 128
#define HEAD_DIM 32
#define NB_SCAN ((N_NODES + 255) / 256) /* 196 */

typedef __attribute__((ext_vector_type(8))) __bf16 bf16x8;
typedef __attribute__((ext_vector_type(4))) __bf16 bf16x4;
typedef __attribute__((ext_vector_type(4))) float f32x4;

// ---- workspace layout (float units) ----
#define SZ_FEAT ((size_t)NUM_RELS * N_NODES * OUT_FEAT)
#define SZ_EL ((size_t)NUM_RELS * N_NODES * N_HEADS)
#define SZ_WB ((size_t)IN_FEAT * 64)
#define SZ_WT ((size_t)NUM_RELS * OUT_FEAT * IN_FEAT / 2)
#define OFF_FEAT ((size_t)0)
#define OFF_EL (OFF_FEAT + SZ_FEAT)
#define OFF_ER (OFF_EL + SZ_EL)
#define OFF_WB (OFF_ER + SZ_EL)
#define OFF_WT (OFF_WB + SZ_WB)
#define OFF_INT (OFF_WT + SZ_WT)
#define IOFF_CNT ((size_t)0)
#define IOFF_PTR ((size_t)N_NODES)
#define IOFF_CUR ((size_t)2 * N_NODES)
#define IOFF_BSUM ((size_t)3 * N_NODES)
#define IOFF_SPAY ((size_t)3 * N_NODES + 256)

// folded attention vectors, transposed bf16: wbt[col][k], col = side*32+r*4+h
__global__ void k_wboth(const float* __restrict__ cw, const float* __restrict__ al,
                        const float* __restrict__ ar, __bf16* __restrict__ wbt) {
    int tid = blockIdx.x * blockDim.x + threadIdx.x;
    if (tid >= IN_FEAT * 64) return;
    int col = tid >> 8, i = tid & 255;
    int side = col >> 5, r = (col >> 2) & 7, h = col & 3;
    const float* av = (side ? ar : al) + (size_t)(r * N_HEADS + h) * HEAD_DIM;
    const float* cwp = cw + ((size_t)(r * N_HEADS + h) * IN_FEAT + i) * HEAD_DIM;
    float s = 0.f;
#pragma unroll
    for (int d = 0; d < HEAD_DIM; ++d) s += cwp[d] * av[d];
    wbt[(size_t)col * IN_FEAT + i] = (__bf16)s;
}

// wt[r][o][k] = bf16(cw[r][h][k][d]), o = h*32+d
__global__ void k_cvt_w(const float* __restrict__ cw, __bf16* __restrict__ wt) {
    int tid = blockIdx.x * blockDim.x + threadIdx.x;
    if (tid >= NUM_RELS * N_HEADS * IN_FEAT * HEAD_DIM) return;
    int d = tid & 31, k = (tid >> 5) & 255, h = (tid >> 13) & 3, r = tid >> 15;
    float v = cw[tid];
    wt[((size_t)(r * OUT_FEAT + h * HEAD_DIM + d)) * IN_FEAT + k] = (__bf16)v;
}

// Fused (R6-proven): X staged once per 128-node tile (full K=256 bf16, swizzled),
// then 8 rel GEMM passes (feat) + 1 folded-attn pass (el/er). 4 waves as 2x2.
__global__ __launch_bounds__(256) void k_fused(const float* __restrict__ x,
                                               const __bf16* __restrict__ wt,
                                               const __bf16* __restrict__ wbt,
                                               __bf16* __restrict__ featb,
                                               float* __restrict__ el,
                                               float* __restrict__ er) {
    __shared__ __align__(16) unsigned char sA[65536]; // [128 rows][512B] swizzled
    __shared__ __align__(16) unsigned char sB[16384]; // [128 rows][128B] swizzled
    const int t = threadIdx.x;
    const int lane = t & 63;
    const int w = t >> 6;
    const int wr = w >> 1, wc = w & 1;
    const int n0 = blockIdx.x * 128;

    // ---- stage A once: 128 rows x 256 k, fp32 -> bf16, swizzled ----
#pragma unroll 8
    for (int i = 0; i < 32; ++i) {
        int flat = i * 256 + t;
        int row = flat >> 6;
        int kq = flat & 63;
        int n = n0 + row;
        if (n >= N_NODES) n = N_NODES - 1;
        float4 v = *(const float4*)(x + (size_t)n * IN_FEAT + kq * 4);
        bf16x4 hv;
        hv[0] = (__bf16)v.x; hv[1] = (__bf16)v.y; hv[2] = (__bf16)v.z; hv[3] = (__bf16)v.w;
        int sg = kq >> 1;
        int slot = (sg & ~7) | ((sg & 7) ^ (row & 7));
        *(bf16x4*)(sA + row * 512 + slot * 16 + (kq & 1) * 8) = hv;
    }
    __syncthreads();

    f32x4 acc[4][4];

    // ---- 8 relation passes ----
    for (int r = 0; r < NUM_RELS; ++r) {
#pragma unroll
        for (int i = 0; i < 4; ++i)
#pragma unroll
            for (int j = 0; j < 4; ++j) acc[i][j] = (f32x4){0.f, 0.f, 0.f, 0.f};
        const __bf16* wtr = wt + (size_t)r * OUT_FEAT * IN_FEAT;

        for (int kc = 0; kc < 4; ++kc) {
#pragma unroll
            for (int i = 0; i < 4; ++i) {
                int flat = i * 256 + t;
                int brow = flat >> 3;
                int s = flat & 7;
                int ssrc = s ^ (brow & 7);
                bf16x8 v = *(const bf16x8*)(wtr + (size_t)brow * IN_FEAT + kc * 64 + ssrc * 8);
                *(bf16x8*)(sB + brow * 128 + s * 16) = v;
            }
            __syncthreads();
#pragma unroll
            for (int ks = 0; ks < 2; ++ks) {
                bf16x8 af[4], bg[4];
#pragma unroll
                for (int rb = 0; rb < 4; ++rb) {
                    int row = wr * 64 + rb * 16 + (lane & 15);
                    int slot = kc * 8 + ((ks * 4 + (lane >> 4)) ^ (row & 7));
                    af[rb] = *(const bf16x8*)(sA + row * 512 + slot * 16);
                }
#pragma unroll
                for (int cb = 0; cb < 4; ++cb) {
                    int brow = wc * 64 + cb * 16 + (lane & 15);
                    int slot = (ks * 4 + (lane >> 4)) ^ (brow & 7);
                    bg[cb] = *(const bf16x8*)(sB + brow * 128 + slot * 16);
                }
#pragma unroll
                for (int rb = 0; rb < 4; ++rb)
#pragma unroll
                    for (int cb = 0; cb < 4; ++cb)
                        acc[rb][cb] = __builtin_amdgcn_mfma_f32_16x16x32_bf16(af[rb], bg[cb], acc[rb][cb], 0, 0, 0);
            }
            __syncthreads();
        }
        // epilogue rel r (C map: col=lane&15, row=(lane>>4)*4+q)
#pragma unroll
        for (int rb = 0; rb < 4; ++rb) {
#pragma unroll
            for (int q = 0; q < 4; ++q) {
                int row = wr * 64 + rb * 16 + (lane >> 4) * 4 + q;
                int n = n0 + row;
                if (n < N_NODES) {
                    __bf16* fp = featb + ((size_t)r * N_NODES + n) * OUT_FEAT + wc * 64 + (lane & 15);
#pragma unroll
                    for (int cb = 0; cb < 4; ++cb) fp[cb * 16] = (__bf16)acc[rb][cb][q];
                }
            }
        }
    }

    // ---- el/er pass: B = wbt[64 cols][256 k]; waves tile 128 rows x 64 cols ----
#pragma unroll
    for (int i = 0; i < 4; ++i)
#pragma unroll
        for (int j = 0; j < 2; ++j) acc[i][j] = (f32x4){0.f, 0.f, 0.f, 0.f};

    for (int kc = 0; kc < 4; ++kc) {
#pragma unroll
        for (int i = 0; i < 2; ++i) {
            int flat = i * 256 + t;
            int brow = flat >> 3;
            int s = flat & 7;
            int ssrc = s ^ (brow & 7);
            bf16x8 v = *(const bf16x8*)(wbt + (size_t)brow * IN_FEAT + kc * 64 + ssrc * 8);
            *(bf16x8*)(sB + brow * 128 + s * 16) = v;
        }
        __syncthreads();
#pragma unroll
        for (int ks = 0; ks < 2; ++ks) {
            bf16x8 af[4], bg[2];
#pragma unroll
            for (int rb = 0; rb < 4; ++rb) {
                int row = wr * 64 + rb * 16 + (lane & 15);
                int slot = kc * 8 + ((ks * 4 + (lane >> 4)) ^ (row & 7));
                af[rb] = *(const bf16x8*)(sA + row * 512 + slot * 16);
            }
#pragma unroll
            for (int cb = 0; cb < 2; ++cb) {
                int brow = wc * 32 + cb * 16 + (lane & 15);
                int slot = (ks * 4 + (lane >> 4)) ^ (brow & 7);
                bg[cb] = *(const bf16x8*)(sB + brow * 128 + slot * 16);
            }
#pragma unroll
            for (int rb = 0; rb < 4; ++rb)
#pragma unroll
                for (int cb = 0; cb < 2; ++cb)
                    acc[rb][cb] = __builtin_amdgcn_mfma_f32_16x16x32_bf16(af[rb], bg[cb], acc[rb][cb], 0, 0, 0);
        }
        __syncthreads();
    }
#pragma unroll
    for (int rb = 0; rb < 4; ++rb) {
#pragma unroll
        for (int q = 0; q < 4; ++q) {
            int n = n0 + wr * 64 + rb * 16 + (lane >> 4) * 4 + q;
            if (n < N_NODES) {
#pragma unroll
                for (int cb = 0; cb < 2; ++cb) {
                    int c = wc * 32 + cb * 16 + (lane & 15);
                    int side = c >> 5, rr = (c >> 2) & 7, h = c & 3;
                    float* dst = side ? er : el;
                    dst[((size_t)rr * N_NODES + n) * N_HEADS + h] = acc[rb][cb][q];
                }
            }
        }
    }
}

// ---- CSR build ----
__global__ void k_hist(const int* __restrict__ col, int* __restrict__ cnt) {
    int e = blockIdx.x * blockDim.x + threadIdx.x;
    if (e < N_EDGES) atomicAdd(cnt + col[e], 1);
}

__global__ __launch_bounds__(256) void k_scanA(const int* __restrict__ cnt,
                                               int* __restrict__ excl,
                                               int* __restrict__ bsum) {
    __shared__ int s[256];
    int i = blockIdx.x * 256 + threadIdx.x;
    int v = (i < N_NODES) ? cnt[i] : 0;
    s[threadIdx.x] = v;
    __syncthreads();
#pragma unroll
    for (int off = 1; off < 256; off <<= 1) {
        int t = (threadIdx.x >= off) ? s[threadIdx.x - off] : 0;
        __syncthreads();
        s[threadIdx.x] += t;
        __syncthreads();
    }
    if (i < N_NODES) excl[i] = s[threadIdx.x] - v;
    if (threadIdx.x == 255) bsum[blockIdx.x] = s[255];
}

__global__ __launch_bounds__(256) void k_scanB(int* __restrict__ bsum) {
    __shared__ int s[256];
    int v = (threadIdx.x < NB_SCAN) ? bsum[threadIdx.x] : 0;
    s[threadIdx.x] = v;
    __syncthreads();
#pragma unroll
    for (int off = 1; off < 256; off <<= 1) {
        int t = (threadIdx.x >= off) ? s[threadIdx.x - off] : 0;
        __syncthreads();
        s[threadIdx.x] += t;
        __syncthreads();
    }
    bsum[threadIdx.x] = s[threadIdx.x] - v;
}

__global__ __launch_bounds__(256) void k_scanC(int* __restrict__ ptr,
                                               int* __restrict__ cursor,
                                               const int* __restrict__ bsum) {
    int i = blockIdx.x * 256 + threadIdx.x;
    if (i >= N_NODES) return;
    int p = ptr[i] + bsum[blockIdx.x];
    ptr[i] = p;
    cursor[i] = p;
}

__global__ void k_scatter(const int* __restrict__ row, const int* __restrict__ col,
                          int* __restrict__ cursor, int* __restrict__ spay) {
    int e = blockIdx.x * blockDim.x + threadIdx.x;
    if (e >= N_EDGES) return;
    int c = col[e];
    int pos = atomicAdd(cursor + c, 1);
    spay[pos] = row[e] | ((e / EPR) << 20);
}

// pull-aggregation v3: 2 waves per node (parity p walks [p*len/2, ...)),
// R5-proven per-edge body (float2/lane, 4-deep pipeline), LDS merge, no atomics.
// N_NODES even -> grid*2 == N_NODES exactly, all threads reach the barrier.
__global__ __launch_bounds__(256) void k_agg(const int* __restrict__ ptr,
                                             const int* __restrict__ cnt,
                                             const int* __restrict__ spay,
                                             const float* __restrict__ el,
                                             const float* __restrict__ er,
                                             const __bf16* __restrict__ featb,
                                             const float* __restrict__ bias,
                                             float* __restrict__ out) {
    __shared__ float part[2][132]; // [local node][128 acc + 4 den]
    const int wv = threadIdx.x >> 6, lane = threadIdx.x & 63;
    const int ln = wv >> 1;   // local node 0..1
    const int par = wv & 1;   // edge-list half
    const int n = blockIdx.x * 2 + ln;
    const int start = ptr[n], len = cnt[n];
    const int h = lane >> 4;
    const int j0 = par ? (len >> 1) : 0;
    const int j1 = par ? len : (len >> 1);
    float accx = 0.f, accy = 0.f, den = 0.f;
    int j = j0;
    for (; j + 4 <= j1; j += 4) {
        int p[4];
#pragma unroll
        for (int u = 0; u < 4; ++u) p[u] = spay[start + j + u];
        float w[4], vx[4], vy[4];
#pragma unroll
        for (int u = 0; u < 4; ++u) {
            int rw = p[u] & 0xFFFFF, r = p[u] >> 20;
            size_t rb = (size_t)r * N_NODES;
            float s = el[(rb + rw) * N_HEADS + h] + er[(rb + n) * N_HEADS + h];
            s = s > 0.f ? s : 0.2f * s;
            w[u] = __expf(s);
            ushort2 raw = *(const ushort2*)(featb + (rb + rw) * OUT_FEAT + lane * 2);
            vx[u] = __uint_as_float((unsigned)raw.x << 16);
            vy[u] = __uint_as_float((unsigned)raw.y << 16);
        }
#pragma unroll
        for (int u = 0; u < 4; ++u) {
            accx += w[u] * vx[u];
            accy += w[u] * vy[u];
            den += w[u];
        }
    }
    for (; j < j1; ++j) {
        int p = spay[start + j];
        int rw = p & 0xFFFFF, r = p >> 20;
        size_t rb = (size_t)r * N_NODES;
        float s = el[(rb + rw) * N_HEADS + h] + er[(rb + n) * N_HEADS + h];
        s = s > 0.f ? s : 0.2f * s;
        float w = __expf(s);
        ushort2 raw = *(const ushort2*)(featb + (rb + rw) * OUT_FEAT + lane * 2);
        accx += w * __uint_as_float((unsigned)raw.x << 16);
        accy += w * __uint_as_float((unsigned)raw.y << 16);
        den += w;
    }
    if (par == 1) {
        part[ln][lane * 2] = accx;
        part[ln][lane * 2 + 1] = accy;
        if ((lane & 15) == 0) part[ln][128 + h] = den;
    }
    __syncthreads();
    if (par == 0) {
        accx += part[ln][lane * 2];
        accy += part[ln][lane * 2 + 1];
        den += part[ln][128 + h];
        float inv = (len > 0) ? 1.f / den : 0.f;
        int o = lane * 2;
        float2 res;
        res.x = accx * inv + bias[o];
        res.y = accy * inv + bias[o + 1];
        *(float2*)(out + (size_t)n * OUT_FEAT + o) = res;
    }
}

extern "C" void kernel_launch(void* const* d_in, const int* in_sizes, int n_in,
                              void* d_out, int out_size, void* d_ws, size_t ws_size,
                              hipStream_t stream) {
    const float* x = (const float*)d_in[0];
    const float* cw = (const float*)d_in[1];
    const float* al = (const float*)d_in[2];
    const float* ar = (const float*)d_in[3];
    const float* bias = (const float*)d_in[4];
    const int* row = (const int*)d_in[5];
    const int* col = (const int*)d_in[6];
    float* out = (float*)d_out;
    float* ws = (float*)d_ws;

    __bf16* featb = (__bf16*)(ws + OFF_FEAT);
    float* el = ws + OFF_EL;
    float* er = ws + OFF_ER;
    __bf16* wbt = (__bf16*)(ws + OFF_WB);
    __bf16* wt = (__bf16*)(ws + OFF_WT);
    int* iw = (int*)(ws + OFF_INT);
    int* cnt = iw + IOFF_CNT;
    int* ptr = iw + IOFF_PTR;
    int* cur = iw + IOFF_CUR;
    int* bsum = iw + IOFF_BSUM;
    int* spay = iw + IOFF_SPAY;

    hipMemsetAsync(cnt, 0, N_NODES * sizeof(int), stream);

    k_wboth<<<(IN_FEAT * 64 + 255) / 256, 256, 0, stream>>>(cw, al, ar, wbt);
    k_cvt_w<<<(NUM_RELS * N_HEADS * IN_FEAT * HEAD_DIM + 255) / 256, 256, 0, stream>>>(cw, wt);
    k_fused<<<(N_NODES + 127) / 128, 256, 0, stream>>>(x, wt, wbt, featb, el, er);

    k_hist<<<(N_EDGES + 255) / 256, 256, 0, stream>>>(col, cnt);
    k_scanA<<<NB_SCAN, 256, 0, stream>>>(cnt, ptr, bsum);
    k_scanB<<<1, 256, 0, stream>>>(bsum);
    k_scanC<<<NB_SCAN, 256, 0, stream>>>(ptr, cur, bsum);
    k_scatter<<<(N_EDGES + 255) / 256, 256, 0, stream>>>(row, col, cur, spay);

    k_agg<<<N_NODES / 2, 256, 0, stream>>>(ptr, cnt, spay, el, er, featb, bias, out);
}